// Round 1
// baseline (591.842 us; speedup 1.0000x reference)
//
#include <hip/hip_runtime.h>
#include <cstdint>
#include <cstddef>

#define TT 1000
#define NB 64000  // B*T = 64*1000

// ---------------------------------------------------------------------------
// GEMM: Z[n,o] = sum_c W[o,c] * S[n,c]
// S: [N, K] u8 (0/1), W: [O, K] f32 row-major, Z: [N, O] f32
// 128x128 tile, BK=16, 256 threads, 8x8 per thread as 2x2 quads of 4
// (quad layout keeps LDS compute reads at <=2-way bank aliasing = free)
// K accumulated in ascending order to mirror naive einsum summation.
// ---------------------------------------------------------------------------
__global__ __launch_bounds__(256) void gemm_spike(
    const uint8_t* __restrict__ S, const float* __restrict__ W,
    float* __restrict__ Z, int K, int O) {
  __shared__ __align__(16) float As[16][128];
  __shared__ __align__(16) float Bs[16][128];
  const int t = threadIdx.x;
  const int bn = blockIdx.x * 128;
  const int bo = blockIdx.y * 128;
  const int tx4 = (t & 15) * 4;
  const int ty4 = ((t >> 4) & 15) * 4;

  const int srow = t >> 1;       // 0..127
  const int skq = (t & 1) * 8;   // 0 or 8

  float acc[8][8];
#pragma unroll
  for (int j = 0; j < 8; j++)
#pragma unroll
    for (int i = 0; i < 8; i++) acc[j][i] = 0.f;

  for (int k0 = 0; k0 < K; k0 += 16) {
    // A tile: 128n x 16k u8 -> float
    {
      const uint8_t* sp = S + (size_t)(bn + srow) * K + (k0 + skq);
      uint2 v = *(const uint2*)sp;
#pragma unroll
      for (int j = 0; j < 4; j++)
        As[skq + j][srow] = (float)((v.x >> (8 * j)) & 0xffu);
#pragma unroll
      for (int j = 0; j < 4; j++)
        As[skq + 4 + j][srow] = (float)((v.y >> (8 * j)) & 0xffu);
    }
    // B tile: Bs[k][o] = W[bo+o][k0+k], guard o rows for O=35
    {
      float4 w0 = make_float4(0.f, 0.f, 0.f, 0.f), w1 = w0;
      if (bo + srow < O) {
        const float* wp = W + (size_t)(bo + srow) * K + (k0 + skq);
        w0 = *(const float4*)wp;
        w1 = *(const float4*)(wp + 4);
      }
      Bs[skq + 0][srow] = w0.x; Bs[skq + 1][srow] = w0.y;
      Bs[skq + 2][srow] = w0.z; Bs[skq + 3][srow] = w0.w;
      Bs[skq + 4][srow] = w1.x; Bs[skq + 5][srow] = w1.y;
      Bs[skq + 6][srow] = w1.z; Bs[skq + 7][srow] = w1.w;
    }
    __syncthreads();
#pragma unroll
    for (int kk = 0; kk < 16; kk++) {
      float4 a0 = *(const float4*)&As[kk][ty4];
      float4 a1 = *(const float4*)&As[kk][64 + ty4];
      float4 b0 = *(const float4*)&Bs[kk][tx4];
      float4 b1 = *(const float4*)&Bs[kk][64 + tx4];
      float av[8] = {a0.x, a0.y, a0.z, a0.w, a1.x, a1.y, a1.z, a1.w};
      float bv[8] = {b0.x, b0.y, b0.z, b0.w, b1.x, b1.y, b1.z, b1.w};
#pragma unroll
      for (int j = 0; j < 8; j++)
#pragma unroll
        for (int i = 0; i < 8; i++)
          acc[j][i] = fmaf(av[j], bv[i], acc[j][i]);
    }
    __syncthreads();
  }
  // store (N=64000 is a multiple of 128: no n guard)
#pragma unroll
  for (int jp = 0; jp < 2; jp++) {
#pragma unroll
    for (int j = 0; j < 4; j++) {
      int n = bn + jp * 64 + ty4 + j;
#pragma unroll
      for (int ip = 0; ip < 2; ip++) {
        int o0 = bo + ip * 64 + tx4;
        float* zp = Z + (size_t)n * O + o0;
        const float* a = &acc[jp * 4 + j][ip * 4];
        if (((O & 3) == 0) && (o0 + 3 < O)) {
          *(float4*)zp = make_float4(a[0], a[1], a[2], a[3]);
        } else {
#pragma unroll
          for (int i = 0; i < 4; i++)
            if (o0 + i < O) zp[i] = a[i];
        }
      }
    }
  }
}

// ---------------------------------------------------------------------------
// CUBA LIF recurrence: one thread per neuron (b,o), sequential over T.
// Z layout [b*T + t][O] -> per-step coalesced loads.
// Mid layers write u8 spikes in same layout; final writes f32 [B,O,T] d_out.
// Non-fused mul/add to mirror numpy's op-by-op fp32 semantics.
// ---------------------------------------------------------------------------
template <bool FINAL>
__global__ __launch_bounds__(64) void cuba_kernel(
    const float* __restrict__ Z, uint8_t* __restrict__ Sout,
    float* __restrict__ Fout, unsigned int* __restrict__ cnt, int O,
    int total) {
  int gid = blockIdx.x * 64 + threadIdx.x;
  unsigned int c = 0;
  if (gid < total) {
    int b = gid / O;
    int o = gid - b * O;
    const float* zp = Z + (size_t)b * TT * O + o;
    uint8_t* sp = nullptr;
    float* fp = nullptr;
    if (FINAL)
      fp = Fout + ((size_t)b * O + o) * TT;
    else
      sp = Sout + (size_t)b * TT * O + o;
    float cur = 0.f, volt = 0.f;
#pragma unroll 8
    for (int t = 0; t < TT; t++) {
      float z = zp[(size_t)t * O];
      cur = __fadd_rn(__fmul_rn(0.75f, cur), z);
      volt = __fadd_rn(__fmul_rn(0.97f, volt), cur);
      bool fire = volt >= 1.25f;
      float s = fire ? 1.f : 0.f;
      volt = fire ? 0.f : volt;
      c += fire ? 1u : 0u;
      if (FINAL)
        fp[t] = s;
      else
        sp[(size_t)t * O] = (uint8_t)(fire ? 1 : 0);
    }
  }
#pragma unroll
  for (int off = 32; off; off >>= 1) c += __shfl_down(c, off, 64);
  if ((threadIdx.x & 63) == 0) atomicAdd(cnt, c);
}

// ---------------------------------------------------------------------------
// Input transpose: [B, 20, T] f32 -> [B*T, 32] u8 (zero-padded K)
// ---------------------------------------------------------------------------
__global__ __launch_bounds__(256) void prep_input(const float* __restrict__ X,
                                                  uint8_t* __restrict__ Sp) {
  int gid = blockIdx.x * 256 + threadIdx.x;  // b*T + t
  if (gid >= NB) return;
  int b = gid / TT, tt = gid - b * TT;
  unsigned int w[8];
#pragma unroll
  for (int i = 0; i < 8; i++) w[i] = 0u;
#pragma unroll
  for (int c = 0; c < 20; c++) {
    float v = X[((size_t)b * 20 + c) * TT + tt];
    unsigned int bit = (v != 0.f) ? 1u : 0u;
    w[c >> 2] |= bit << ((c & 3) * 8);
  }
  uint4* dst = (uint4*)(Sp + (size_t)gid * 32);
  dst[0] = make_uint4(w[0], w[1], w[2], w[3]);
  dst[1] = make_uint4(w[4], w[5], w[6], w[7]);
}

// W1 [256,20] -> padded [256,32]
__global__ __launch_bounds__(256) void pad_w1(const float* __restrict__ W,
                                              float* __restrict__ Wp) {
  int i = blockIdx.x * 256 + threadIdx.x;
  if (i >= 256 * 32) return;
  int o = i >> 5, c = i & 31;
  Wp[i] = (c < 20) ? W[o * 20 + c] : 0.f;
}

__global__ void finalize_counts(const unsigned int* __restrict__ cnt,
                                float* __restrict__ out) {
  int i = threadIdx.x;
  if (i < 4) {
    const float denom[4] = {16384000.f, 16384000.f, 16384000.f, 2240000.f};
    out[i] = (float)cnt[i] / denom[i];
  }
}

// ---------------------------------------------------------------------------
extern "C" void kernel_launch(void* const* d_in, const int* in_sizes, int n_in,
                              void* d_out, int out_size, void* d_ws,
                              size_t ws_size, hipStream_t stream) {
  const float* X = (const float*)d_in[0];
  const float* W1 = (const float*)d_in[1];
  const float* W2 = (const float*)d_in[2];
  const float* W3 = (const float*)d_in[3];
  const float* W4 = (const float*)d_in[4];
  float* out = (float*)d_out;

  char* ws = (char*)d_ws;
  unsigned int* cnt = (unsigned int*)ws;                        // 256 B reserved
  float* Z = (float*)(ws + 256);                                // 65,536,000 B
  uint8_t* Sa = (uint8_t*)(ws + 256 + 65536000ull);             // 16,384,000 B
  uint8_t* Sb = Sa + 16384000ull;                               // 16,384,000 B
  uint8_t* Sin = Sb + 16384000ull;                              // 2,048,000 B
  float* W1p = (float*)(Sin + 2048000ull);                      // 32,768 B

  hipMemsetAsync(cnt, 0, 16, stream);
  pad_w1<<<32, 256, 0, stream>>>(W1, W1p);
  prep_input<<<(NB + 255) / 256, 256, 0, stream>>>(X, Sin);

  dim3 gBig(NB / 128, 2);  // O=256 -> 2 col-blocks
  dim3 gOut(NB / 128, 1);  // O=35  -> 1 col-block

  // layer 1: K=32(pad), O=256
  gemm_spike<<<gBig, 256, 0, stream>>>(Sin, W1p, Z, 32, 256);
  cuba_kernel<false><<<16384 / 64, 64, 0, stream>>>(Z, Sa, nullptr, cnt + 0,
                                                    256, 16384);
  // layer 2
  gemm_spike<<<gBig, 256, 0, stream>>>(Sa, W2, Z, 256, 256);
  cuba_kernel<false><<<16384 / 64, 64, 0, stream>>>(Z, Sb, nullptr, cnt + 1,
                                                    256, 16384);
  // layer 3
  gemm_spike<<<gBig, 256, 0, stream>>>(Sb, W3, Z, 256, 256);
  cuba_kernel<false><<<16384 / 64, 64, 0, stream>>>(Z, Sa, nullptr, cnt + 2,
                                                    256, 16384);
  // layer 4: O=35
  gemm_spike<<<gOut, 256, 0, stream>>>(Sa, W4, Z, 256, 35);
  cuba_kernel<true><<<2240 / 64, 64, 0, stream>>>(Z, nullptr, out, cnt + 3, 35,
                                                  2240);
  finalize_counts<<<1, 64, 0, stream>>>(cnt, out + 2240000);
}

// Round 2
// 530.336 us; speedup vs baseline: 1.1160x; 1.1160x over previous
//
#include <hip/hip_runtime.h>
#include <cstdint>
#include <cstddef>

#define TT 1000
#define NB 64000  // B*T

// ---------------------------------------------------------------------------
// gemm128: Z[n,o] = sum_k Wt[k][o] * S[n][k]   (O == 256 callers only)
// S: [N,K] u8; Wt: [K,O] f32 (pre-transposed); Z: [N,O] f32
// 128n x 128o tile, BK=16, 256 thr, 8x8/thread.
// Double-buffered LDS, register prefetch, ONE barrier per k-tile.
// Accumulation: single ascending-k fmaf chain per output (bit-exact vs ref).
// ---------------------------------------------------------------------------
__global__ __launch_bounds__(256) void gemm128(
    const uint8_t* __restrict__ S, const float* __restrict__ Wt,
    float* __restrict__ Z, int K, int O) {
  __shared__ __align__(16) float As[2][16][128];
  __shared__ __align__(16) float Bs[2][16][128];
  const int t = threadIdx.x;
  const int bn = blockIdx.x * 128;
  const int bo = blockIdx.y * 128;
  const int tx4 = (t & 15) * 4;
  const int ty4 = ((t >> 4) & 15) * 4;
  const int srow = t >> 1;      // 0..127 (A-staging row)
  const int skq = (t & 1) * 8;  // 0 or 8

  // B staging: flat contiguous copy (conflict-free, coalesced both sides)
  const int bf0 = t * 4;         // float index 0..1023
  const int bf1 = 1024 + t * 4;  // 1024..2047
  const int bk0 = bf0 >> 7, bc0 = bf0 & 127;
  const int bk1 = bf1 >> 7, bc1 = bf1 & 127;

  float acc[8][8];
#pragma unroll
  for (int j = 0; j < 8; j++)
#pragma unroll
    for (int i = 0; i < 8; i++) acc[j][i] = 0.f;

  const int ntiles = K >> 4;
  const uint8_t* sprow = S + (size_t)(bn + srow) * K;

  // prologue: stage tile 0
  {
    uint2 av = *(const uint2*)(sprow + skq);
    float4 b0 = *(const float4*)(Wt + (size_t)bk0 * O + bo + bc0);
    float4 b1 = *(const float4*)(Wt + (size_t)bk1 * O + bo + bc1);
#pragma unroll
    for (int j = 0; j < 4; j++)
      As[0][skq + j][srow] = (float)((av.x >> (8 * j)) & 0xffu);
#pragma unroll
    for (int j = 0; j < 4; j++)
      As[0][skq + 4 + j][srow] = (float)((av.y >> (8 * j)) & 0xffu);
    *(float4*)&Bs[0][bk0][bc0] = b0;
    *(float4*)&Bs[0][bk1][bc1] = b1;
  }
  __syncthreads();

  for (int tile = 0; tile < ntiles; tile++) {
    const int cur = tile & 1, nxt = cur ^ 1;
    const int k1 = (tile + 1) << 4;
    uint2 av;
    float4 pb0, pb1;
    const bool more = (tile + 1 < ntiles);
    if (more) {  // issue next-tile global loads before compute
      av = *(const uint2*)(sprow + k1 + skq);
      pb0 = *(const float4*)(Wt + (size_t)(k1 + bk0) * O + bo + bc0);
      pb1 = *(const float4*)(Wt + (size_t)(k1 + bk1) * O + bo + bc1);
    }
#pragma unroll
    for (int kk = 0; kk < 16; kk++) {
      float4 a0 = *(const float4*)&As[cur][kk][ty4];
      float4 a1 = *(const float4*)&As[cur][kk][64 + ty4];
      float4 b0 = *(const float4*)&Bs[cur][kk][tx4];
      float4 b1 = *(const float4*)&Bs[cur][kk][64 + tx4];
      float avv[8] = {a0.x, a0.y, a0.z, a0.w, a1.x, a1.y, a1.z, a1.w};
      float bvv[8] = {b0.x, b0.y, b0.z, b0.w, b1.x, b1.y, b1.z, b1.w};
#pragma unroll
      for (int j = 0; j < 8; j++)
#pragma unroll
        for (int i = 0; i < 8; i++)
          acc[j][i] = fmaf(avv[j], bvv[i], acc[j][i]);
    }
    if (more) {
#pragma unroll
      for (int j = 0; j < 4; j++)
        As[nxt][skq + j][srow] = (float)((av.x >> (8 * j)) & 0xffu);
#pragma unroll
      for (int j = 0; j < 4; j++)
        As[nxt][skq + 4 + j][srow] = (float)((av.y >> (8 * j)) & 0xffu);
      *(float4*)&Bs[nxt][bk0][bc0] = pb0;
      *(float4*)&Bs[nxt][bk1][bc1] = pb1;
    }
    __syncthreads();
  }

  // store (O == 256, N multiple of 128)
#pragma unroll
  for (int jp = 0; jp < 2; jp++) {
#pragma unroll
    for (int j = 0; j < 4; j++) {
      int n = bn + jp * 64 + ty4 + j;
#pragma unroll
      for (int ip = 0; ip < 2; ip++) {
        int o0 = bo + ip * 64 + tx4;
        const float* a = &acc[jp * 4 + j][ip * 4];
        *(float4*)(Z + (size_t)n * O + o0) =
            make_float4(a[0], a[1], a[2], a[3]);
      }
    }
  }
}

// ---------------------------------------------------------------------------
// gemm64: layer-4 variant. 128n x 64o tile, stores only o<35, Z stride 35.
// Wt4: [256][64] f32 zero-padded. Same exact accumulation chain.
// ---------------------------------------------------------------------------
__global__ __launch_bounds__(256) void gemm64(const uint8_t* __restrict__ S,
                                              const float* __restrict__ Wt,
                                              float* __restrict__ Z) {
  const int K = 256, OP = 64, OS = 35;
  __shared__ __align__(16) float As[2][16][128];
  __shared__ __align__(16) float Bs[2][16][64];
  const int t = threadIdx.x;
  const int bn = blockIdx.x * 128;
  const int tx4 = (t & 15) * 4;
  const int ty4 = ((t >> 4) & 15) * 4;
  const int srow = t >> 1;
  const int skq = (t & 1) * 8;
  const int bf = t * 4;  // 0..1023 floats == whole 16x64 tile
  const int bk = bf >> 6, bc = bf & 63;

  float acc[8][4];
#pragma unroll
  for (int j = 0; j < 8; j++)
#pragma unroll
    for (int i = 0; i < 4; i++) acc[j][i] = 0.f;

  const uint8_t* sprow = S + (size_t)(bn + srow) * K;
  {
    uint2 av = *(const uint2*)(sprow + skq);
    float4 b = *(const float4*)(Wt + (size_t)bk * OP + bc);
#pragma unroll
    for (int j = 0; j < 4; j++)
      As[0][skq + j][srow] = (float)((av.x >> (8 * j)) & 0xffu);
#pragma unroll
    for (int j = 0; j < 4; j++)
      As[0][skq + 4 + j][srow] = (float)((av.y >> (8 * j)) & 0xffu);
    *(float4*)&Bs[0][bk][bc] = b;
  }
  __syncthreads();

  const int ntiles = K >> 4;
  for (int tile = 0; tile < ntiles; tile++) {
    const int cur = tile & 1, nxt = cur ^ 1;
    const int k1 = (tile + 1) << 4;
    uint2 av;
    float4 pb;
    const bool more = (tile + 1 < ntiles);
    if (more) {
      av = *(const uint2*)(sprow + k1 + skq);
      pb = *(const float4*)(Wt + (size_t)(k1 + bk) * OP + bc);
    }
#pragma unroll
    for (int kk = 0; kk < 16; kk++) {
      float4 a0 = *(const float4*)&As[cur][kk][ty4];
      float4 a1 = *(const float4*)&As[cur][kk][64 + ty4];
      float4 b0 = *(const float4*)&Bs[cur][kk][tx4];
      float avv[8] = {a0.x, a0.y, a0.z, a0.w, a1.x, a1.y, a1.z, a1.w};
      float bvv[4] = {b0.x, b0.y, b0.z, b0.w};
#pragma unroll
      for (int j = 0; j < 8; j++)
#pragma unroll
        for (int i = 0; i < 4; i++)
          acc[j][i] = fmaf(avv[j], bvv[i], acc[j][i]);
    }
    if (more) {
#pragma unroll
      for (int j = 0; j < 4; j++)
        As[nxt][skq + j][srow] = (float)((av.x >> (8 * j)) & 0xffu);
#pragma unroll
      for (int j = 0; j < 4; j++)
        As[nxt][skq + 4 + j][srow] = (float)((av.y >> (8 * j)) & 0xffu);
      *(float4*)&Bs[nxt][bk][bc] = pb;
    }
    __syncthreads();
  }

#pragma unroll
  for (int jp = 0; jp < 2; jp++) {
#pragma unroll
    for (int j = 0; j < 4; j++) {
      int n = bn + jp * 64 + ty4 + j;
#pragma unroll
      for (int i = 0; i < 4; i++) {
        int o = tx4 + i;
        if (o < OS) Z[(size_t)n * OS + o] = acc[jp * 4 + j][i];
      }
    }
  }
}

// ---------------------------------------------------------------------------
// CUBA LIF recurrence, 2-deep pipelined loads (20-element batches).
// Exact per-step fp32 mul/add as before (bit-exact vs r1 which matched ref).
// ---------------------------------------------------------------------------
template <bool FINAL>
__global__ __launch_bounds__(64) void cuba_kernel(
    const float* __restrict__ Z, uint8_t* __restrict__ Sout,
    float* __restrict__ Fout, unsigned int* __restrict__ cnt, int O,
    int total) {
  int gid = blockIdx.x * 64 + threadIdx.x;
  unsigned int c = 0;
  if (gid < total) {
    int b = gid / O;
    int o = gid - b * O;
    const float* zp = Z + (size_t)b * TT * O + o;
    uint8_t* sp = Sout + (size_t)b * TT * O + o;
    float* fp = Fout + ((size_t)b * O + o) * TT;
    float cur = 0.f, volt = 0.f;
    constexpr int U = 20;  // TT = 1000 = 25 * 2U
    float za[U], zb[U];
#pragma unroll
    for (int u = 0; u < U; u++) za[u] = zp[(size_t)u * O];
    for (int t0 = 0; t0 < TT; t0 += 2 * U) {
      if (t0 + U < TT) {
#pragma unroll
        for (int u = 0; u < U; u++) zb[u] = zp[(size_t)(t0 + U + u) * O];
      }
#pragma unroll
      for (int u = 0; u < U; u++) {
        cur = __fadd_rn(__fmul_rn(0.75f, cur), za[u]);
        volt = __fadd_rn(__fmul_rn(0.97f, volt), cur);
        bool fire = volt >= 1.25f;
        volt = fire ? 0.f : volt;
        c += fire ? 1u : 0u;
        if (FINAL)
          fp[t0 + u] = fire ? 1.f : 0.f;
        else
          sp[(size_t)(t0 + u) * O] = (uint8_t)(fire ? 1 : 0);
      }
      if (t0 + 2 * U < TT) {
#pragma unroll
        for (int u = 0; u < U; u++) za[u] = zp[(size_t)(t0 + 2 * U + u) * O];
      }
#pragma unroll
      for (int u = 0; u < U; u++) {
        cur = __fadd_rn(__fmul_rn(0.75f, cur), zb[u]);
        volt = __fadd_rn(__fmul_rn(0.97f, volt), cur);
        bool fire = volt >= 1.25f;
        volt = fire ? 0.f : volt;
        c += fire ? 1u : 0u;
        if (FINAL)
          fp[t0 + U + u] = fire ? 1.f : 0.f;
        else
          sp[(size_t)(t0 + U + u) * O] = (uint8_t)(fire ? 1 : 0);
      }
    }
  }
#pragma unroll
  for (int off = 32; off; off >>= 1) c += __shfl_down(c, off, 64);
  if ((threadIdx.x & 63) == 0) atomicAdd(cnt, c);
}

// ---------------------------------------------------------------------------
// Input: [B,20,T] f32 -> [B*T, 32] u8 (K zero-padded)
// ---------------------------------------------------------------------------
__global__ __launch_bounds__(256) void prep_input(const float* __restrict__ X,
                                                  uint8_t* __restrict__ Sp) {
  int gid = blockIdx.x * 256 + threadIdx.x;
  if (gid >= NB) return;
  int b = gid / TT, tt = gid - b * TT;
  unsigned int w[8];
#pragma unroll
  for (int i = 0; i < 8; i++) w[i] = 0u;
#pragma unroll
  for (int c = 0; c < 20; c++) {
    float v = X[((size_t)b * 20 + c) * TT + tt];
    unsigned int bit = (v != 0.f) ? 1u : 0u;
    w[c >> 2] |= bit << ((c & 3) * 8);
  }
  uint4* dst = (uint4*)(Sp + (size_t)gid * 32);
  dst[0] = make_uint4(w[0], w[1], w[2], w[3]);
  dst[1] = make_uint4(w[4], w[5], w[6], w[7]);
}

// W [O,K] -> Wt [Kpad,Opad] transposed + zero-padded (exact copy of values)
__global__ __launch_bounds__(256) void prep_w(const float* __restrict__ W,
                                              float* __restrict__ Wt, int O,
                                              int K, int Kpad, int Opad) {
  int i = blockIdx.x * 256 + threadIdx.x;
  if (i >= Kpad * Opad) return;
  int k = i / Opad, o = i - k * Opad;
  Wt[i] = (k < K && o < O) ? W[(size_t)o * K + k] : 0.f;
}

__global__ void finalize_counts(const unsigned int* __restrict__ cnt,
                                float* __restrict__ out) {
  int i = threadIdx.x;
  if (i < 4) {
    const float denom[4] = {16384000.f, 16384000.f, 16384000.f, 2240000.f};
    out[i] = (float)cnt[i] / denom[i];
  }
}

// ---------------------------------------------------------------------------
extern "C" void kernel_launch(void* const* d_in, const int* in_sizes, int n_in,
                              void* d_out, int out_size, void* d_ws,
                              size_t ws_size, hipStream_t stream) {
  const float* X = (const float*)d_in[0];
  const float* W1 = (const float*)d_in[1];
  const float* W2 = (const float*)d_in[2];
  const float* W3 = (const float*)d_in[3];
  const float* W4 = (const float*)d_in[4];
  float* out = (float*)d_out;

  char* ws = (char*)d_ws;
  unsigned int* cnt = (unsigned int*)ws;             // 256 B
  float* Z = (float*)(ws + 256);                     // 65,536,000
  uint8_t* Sa = (uint8_t*)(ws + 256 + 65536000ull);  // 16,384,000
  uint8_t* Sb = Sa + 16384000ull;                    // 16,384,000
  uint8_t* Sin = Sb + 16384000ull;                   // 2,048,000
  float* Wt1 = (float*)(Sin + 2048000ull);           // 32*256*4   = 32,768
  float* Wt2 = Wt1 + 32 * 256;                       // 256*256*4  = 262,144
  float* Wt3 = Wt2 + 256 * 256;                      // 262,144
  float* Wt4 = Wt3 + 256 * 256;                      // 256*64*4   = 65,536

  hipMemsetAsync(cnt, 0, 16, stream);
  prep_w<<<(32 * 256 + 255) / 256, 256, 0, stream>>>(W1, Wt1, 256, 20, 32, 256);
  prep_w<<<(256 * 256) / 256, 256, 0, stream>>>(W2, Wt2, 256, 256, 256, 256);
  prep_w<<<(256 * 256) / 256, 256, 0, stream>>>(W3, Wt3, 256, 256, 256, 256);
  prep_w<<<(256 * 64) / 256, 256, 0, stream>>>(W4, Wt4, 35, 256, 256, 64);
  prep_input<<<(NB + 255) / 256, 256, 0, stream>>>(X, Sin);

  dim3 gBig(NB / 128, 2);

  gemm128<<<gBig, 256, 0, stream>>>(Sin, Wt1, Z, 32, 256);
  cuba_kernel<false><<<256, 64, 0, stream>>>(Z, Sa, nullptr, cnt + 0, 256,
                                             16384);
  gemm128<<<gBig, 256, 0, stream>>>(Sa, Wt2, Z, 256, 256);
  cuba_kernel<false><<<256, 64, 0, stream>>>(Z, Sb, nullptr, cnt + 1, 256,
                                             16384);
  gemm128<<<gBig, 256, 0, stream>>>(Sb, Wt3, Z, 256, 256);
  cuba_kernel<false><<<256, 64, 0, stream>>>(Z, Sa, nullptr, cnt + 2, 256,
                                             16384);
  gemm64<<<NB / 128, 256, 0, stream>>>(Sa, Wt4, Z);
  cuba_kernel<true><<<35, 64, 0, stream>>>(Z, nullptr, out, cnt + 3, 35, 2240);
  finalize_counts<<<1, 64, 0, stream>>>(cnt, out + 2240000);
}